// Round 10
// baseline (338.177 us; speedup 1.0000x reference)
//
#include <hip/hip_runtime.h>
#include <cstdint>

using u8  = unsigned char;
using u16 = unsigned short;
using u32 = unsigned int;
using bf16x8 = __attribute__((ext_vector_type(8))) short;
using f32x4  = __attribute__((ext_vector_type(4))) float;

#define CAPB 512        // per-fine-bucket (16 nodes) record capacity
#define CAPC 9216       // per-coarse-bin (512 nodes) record capacity
#define EB   8192       // edges per bin_k block
#define SLSZ 640        // slist capacity (padded)

__device__ __forceinline__ float b2f(u16 b) { return __uint_as_float(((u32)b) << 16); }
__device__ __forceinline__ u16 f2b(float f) {
    u32 u = __float_as_uint(f);
    return (u16)((u + 0x7fff + ((u >> 16) & 1)) >> 16);   // RNE
}
// biased-u8 encode: clamp(rint(x*16),-127,127)+128  ->  [1,255]; 128 == 0.0
__device__ __forceinline__ u32 fq8(float f) {
    float t = fminf(fmaxf(fmaf(f, 16.f, 128.f), 1.f), 255.f);
    return (u32)(t + 0.5f);
}

// ---------------------------------------------------------------- xq (N+1 x 128B) + embq (N+1 x 16B), biased-u8
__global__ __launch_bounds__(256) void build_q8_k(const float* __restrict__ x,
        const float* __restrict__ emb, u8* __restrict__ xq, u8* __restrict__ embq, int N) {
    int t = blockIdx.x * 256 + threadIdx.x;
    if (t >= N * 18) return;
    int i = t / 18, q = t - i * 18;
    const float* s = (q < 16) ? (x + (int64_t)i * 128 + q * 8)
                              : (emb + (int64_t)i * 16 + (q - 16) * 8);
    u32 b0 = fq8(s[0]) | (fq8(s[1]) << 8) | (fq8(s[2]) << 16) | (fq8(s[3]) << 24);
    u32 b1 = fq8(s[4]) | (fq8(s[5]) << 8) | (fq8(s[6]) << 16) | (fq8(s[7]) << 24);
    uint2 w = make_uint2(b0, b1);
    if (q < 16) *reinterpret_cast<uint2*>(xq + (int64_t)i * 128 + q * 8) = w;
    else        *reinterpret_cast<uint2*>(embq + (int64_t)i * 16 + (q - 16) * 8) = w;
}

// ---------------------------------------------------------------- weight B-fragment pack
template<int D>
__global__ __launch_bounds__(256) void pack_w_k(const float* __restrict__ Wl,
        const float* __restrict__ Wr, u16* __restrict__ wp) {
    constexpr int KT = (2 * D) / 32;
    int gid = blockIdx.x * 256 + threadIdx.x;
    if (gid >= KT * 8 * 64) return;
    int lane = gid & 63, nt = (gid >> 6) & 7, kt = gid >> 9;
    int n = nt * 16 + (lane & 15);
    int kb = kt * 32 + ((lane >> 4) & 3) * 8;
    u32 out[4];
    #pragma unroll
    for (int jj = 0; jj < 4; ++jj) {
        int k0 = kb + 2 * jj, k1 = k0 + 1;
        float f0 = (k0 < D) ? Wl[k0 * 128 + n] : Wr[(k0 - D) * 128 + n];
        float f1 = (k1 < D) ? Wl[k1 * 128 + n] : Wr[(k1 - D) * 128 + n];
        out[jj] = (u32)f2b(f0) | ((u32)f2b(f1) << 16);
    }
    *reinterpret_cast<uint4*>(wp + (size_t)gid * 8) = make_uint4(out[0], out[1], out[2], out[3]);
}

// ---------------------------------------------------------------- phase A: coarse bin
__global__ __launch_bounds__(256) void bin_k(const int* __restrict__ eo,
        const int* __restrict__ ei, int E, int nbins_dir,
        int* __restrict__ gcnt, u32* __restrict__ crecs) {
    __shared__ u32 lrec[EB];
    __shared__ u16 lkey[EB];
    __shared__ int lcnt[392], gbase[392], lpos[392];
    const int tid = threadIdx.x;
    const int nbins = 2 * nbins_dir;
    for (int i = tid; i < nbins; i += 256) lcnt[i] = 0;
    __syncthreads();
    const int base = blockIdx.x * EB;
    const int nrec = min(EB, 2 * E - base);
    #pragma unroll 4
    for (int t = tid; t < nrec; t += 256) {
        int g = base + t;
        int dir = (g >= E) ? 1 : 0;
        int e = g - dir * E;
        const int* ed = dir ? ei : eo;
        int s = ed[e], d = ed[E + e];
        int key = dir * nbins_dir + (d >> 9);
        lrec[t] = ((u32)(d & 511) << 20) | (u32)s;
        lkey[t] = (u16)key;
        atomicAdd(&lcnt[key], 1);
    }
    __syncthreads();
    for (int i = tid; i < nbins; i += 256) {
        lpos[i] = 0;
        gbase[i] = lcnt[i] ? atomicAdd(&gcnt[i], lcnt[i]) : 0;
    }
    __syncthreads();
    #pragma unroll 4
    for (int t = tid; t < nrec; t += 256) {
        int key = lkey[t];
        int pos = gbase[key] + atomicAdd(&lpos[key], 1);
        if (pos < CAPC) crecs[(size_t)key * CAPC + pos] = lrec[t];
    }
}

// ---------------------------------------------------------------- phase B: split coarse -> fine
__global__ __launch_bounds__(256) void split_k(const int* __restrict__ gcnt,
        const u32* __restrict__ crecs, int nbins_dir,
        u32* __restrict__ recs_o, int* __restrict__ fcnt_o,
        u32* __restrict__ recs_i, int* __restrict__ fcnt_i) {
    __shared__ u32 lsort[CAPC];
    __shared__ int lcnt[32], lrp[32], lcur[32];
    const int tid = threadIdx.x;
    const int c = blockIdx.x;
    const int dir = c / nbins_dir;
    const int bin = c - dir * nbins_dir;
    u32* recs = dir ? recs_i : recs_o;
    int* fcnt = dir ? fcnt_i : fcnt_o;
    const int n = min(gcnt[c], CAPC);
    const u32* rb = crecs + (size_t)c * CAPC;
    if (tid < 32) { lcnt[tid] = 0; lcur[tid] = 0; }
    __syncthreads();
    for (int t = tid; t < n; t += 256) atomicAdd(&lcnt[rb[t] >> 24], 1);
    __syncthreads();
    if (tid == 0) {
        int run = 0;
        #pragma unroll
        for (int i = 0; i < 32; ++i) { lrp[i] = run; run += lcnt[i]; }
    }
    __syncthreads();
    for (int t = tid; t < n; t += 256) {
        u32 rc = rb[t];
        int fb = rc >> 24;
        lsort[lrp[fb] + atomicAdd(&lcur[fb], 1)] = ((rc >> 20) & 15u) << 27 | (rc & 0xFFFFFu);
    }
    __syncthreads();
    #pragma unroll
    for (int fb = 0; fb < 32; ++fb) {
        int fine = bin * 32 + fb;
        int cnt = min(lcnt[fb], CAPB);
        u32* dst = recs + (size_t)fine * CAPB;
        for (int t = tid; t < cnt; t += 256) dst[t] = lsort[lrp[fb] + t];
        if (tid == 0) fcnt[fine] = cnt;
    }
}

// ---------------------------------------------------------------- fused SAGE layer
// Gather tables are biased-u8 (byte = clamp(rint(v*16),-127,127)+128), stride 128B.
// Quarter-wave owns node wv*4+q; per-node list padded to multiple of 6 with dummy
// node N (all-128 row == 0.0). Depth-6 static ring, unconditional loads, SWAR u8
// accumulate (2x16-bit lanes, flushed to u32 every 240 edges). Bias removed once.
// MFMA GEMM vs packed [Wl;Wr] K=2D. HEAD: +residual (bf16 self), head dot.
template<int D, bool HEAD, bool ACCUM>
__global__ __launch_bounds__(256) void fused_sage(
        const u8* __restrict__ srcq,                 // biased-u8 gather table, stride 128
        const u8* __restrict__ embq,                 // biased-u8 emb table, stride 16 (layer 1)
        const u16* __restrict__ selfb,               // bf16 self table (layer 2)
        const float* __restrict__ xf, const float* __restrict__ ef, // layer-1 self
        const int* __restrict__ bcnt, const u32* __restrict__ recs,
        const u16* __restrict__ wp, const float* __restrict__ bl,
        u16* __restrict__ houtb, u8* __restrict__ houtq,
        float* __restrict__ dout,
        const float* __restrict__ Wseg, const float* __restrict__ linb, int N) {
    constexpr bool EMB = (D == 144);
    constexpr int K = 2 * D;
    constexpr int KT = K / 32;
    constexpr int ROWB = 592;
    __shared__ u16 sAB[16 * (ROWB / 2)];
    __shared__ u32 rbuf[CAPB];
    __shared__ u32 slist[SLSZ];
    __shared__ int ncnt[16], nrp[16], ncur[16];
    __shared__ float ps[4][16];
    const int tid = threadIdx.x;
    const int lane = tid & 63;
    const int wv = tid >> 6;
    const int q = lane >> 4;
    const int ql = lane & 15;
    const int64_t block0 = (int64_t)blockIdx.x * 16;
    const int nrows = (int)min((int64_t)16, (int64_t)N - block0);

    // ---- stage self rows (bf16) at byte offset 2*D; pre-fill slist with dummy N
    for (int t = tid; t < SLSZ; t += 256) slist[t] = (u32)N;
    if (EMB) {
        for (int f = tid; f < 16 * 36; f += 256) {
            int r = f / 36, c = f - r * 36;
            if (r < nrows) {
                float4 v = (c < 32)
                    ? reinterpret_cast<const float4*>(xf)[(block0 + r) * 32 + c]
                    : reinterpret_cast<const float4*>(ef)[(block0 + r) * 4 + (c - 32)];
                u32 lo = (u32)f2b(v.x) | ((u32)f2b(v.y) << 16);
                u32 hi = (u32)f2b(v.z) | ((u32)f2b(v.w) << 16);
                *reinterpret_cast<uint2*>((char*)sAB + r * ROWB + D * 2 + c * 8) = make_uint2(lo, hi);
            }
        }
    } else {
        for (int f = tid; f < 16 * 16; f += 256) {
            int r = f / 16, c = f - r * 16;
            if (r < nrows) {
                uint4 v = reinterpret_cast<const uint4*>(selfb + (block0 + r) * 128)[c];
                *reinterpret_cast<uint4*>((char*)sAB + r * ROWB + D * 2 + c * 16) = v;
            }
        }
    }
    if (tid < 16) ncnt[tid] = 0;

    // ---- load records, counting sort into per-node lists (padded to multiple of 6)
    const int n = min(bcnt[blockIdx.x], CAPB);
    const u32* rb = recs + (size_t)blockIdx.x * CAPB;
    for (int t = tid; t < n; t += 256) rbuf[t] = rb[t];
    __syncthreads();
    for (int t = tid; t < n; t += 256) atomicAdd(&ncnt[rbuf[t] >> 27], 1);
    __syncthreads();
    if (tid == 0) {
        int run = 0;
        #pragma unroll
        for (int i = 0; i < 16; ++i) { nrp[i] = run; run += (ncnt[i] + 5) / 6 * 6; }
    }
    if (tid < 16) ncur[tid] = 0;
    __syncthreads();
    for (int t = tid; t < n; t += 256) {
        u32 rc = rbuf[t];
        int dl = rc >> 27;
        slist[nrp[dl] + atomicAdd(&ncur[dl], 1)] = rc & 0x07ffffffu;
    }
    __syncthreads();

    // ---- gather: quarter q owns node r = wv*4+q; depth-6 ring, SWAR u8 accumulate
    const int r = wv * 4 + q;
    const int cj = ncnt[r];
    const int cjp = (cj + 5) / 6 * 6;
    const int off = nrp[r];
    const u8* basem = srcq + ql * 8;
    const u8* basee = embq + (ql & 7) * 2;
    u32 aE0 = 0, aO0 = 0, aE1 = 0, aO1 = 0;          // 2x16-bit SWAR lanes
    u32 s0 = 0, s1 = 0, s2 = 0, s3 = 0, s4 = 0, s5 = 0, s6 = 0, s7 = 0;  // u32 totals
    u32 te0 = 0, te1 = 0;                            // emb byte sums (u32, no flush)
    {
        uint2 m0, m1, m2, m3, m4, m5;
        u32 t0 = 0, t1 = 0, t2 = 0, t3 = 0, t4 = 0, t5 = 0;
#define LOADK(KK, MM, TT)                                                          \
        {                                                                          \
            u32 so_ = slist[off + (KK)];                                           \
            MM = *reinterpret_cast<const uint2*>(basem + ((size_t)so_ << 7));      \
            if (EMB) TT = (ql < 8) ? (u32)*reinterpret_cast<const u16*>(basee + ((size_t)so_ << 4)) : 0u; \
        }
#define COMMITK(MM, TT)                                                            \
        {                                                                          \
            aE0 += MM.x & 0x00FF00FFu; aO0 += (MM.x >> 8) & 0x00FF00FFu;           \
            aE1 += MM.y & 0x00FF00FFu; aO1 += (MM.y >> 8) & 0x00FF00FFu;           \
            if (EMB) { te0 += TT & 0xffu; te1 += TT >> 8; }                        \
        }
        LOADK(0, m0, t0) LOADK(1, m1, t1) LOADK(2, m2, t2)
        LOADK(3, m3, t3) LOADK(4, m4, t4) LOADK(5, m5, t5)
        for (int k0 = 0; k0 < cjp; k0 += 240) {
            const int ke = min(k0 + 240, cjp);
            for (int k = k0; k < ke; k += 6) {
                COMMITK(m0, t0) LOADK(k + 6,  m0, t0)
                COMMITK(m1, t1) LOADK(k + 7,  m1, t1)
                COMMITK(m2, t2) LOADK(k + 8,  m2, t2)
                COMMITK(m3, t3) LOADK(k + 9,  m3, t3)
                COMMITK(m4, t4) LOADK(k + 10, m4, t4)
                COMMITK(m5, t5) LOADK(k + 11, m5, t5)
            }
            s0 += aE0 & 0xffffu; s2 += aE0 >> 16;
            s1 += aO0 & 0xffffu; s3 += aO0 >> 16;
            s4 += aE1 & 0xffffu; s6 += aE1 >> 16;
            s5 += aO1 & 0xffffu; s7 += aO1 >> 16;
            aE0 = 0; aO0 = 0; aE1 = 0; aO1 = 0;
        }
#undef LOADK
#undef COMMITK
    }

    // ---- de-bias, scale, mean -> bf16 staging row r
    {
        const float scl = 1.0f / (16.0f * (float)max(cj, 1));
        const float nb = -128.0f * (float)cjp * scl;
        float f0 = fmaf((float)s0, scl, nb), f1 = fmaf((float)s1, scl, nb);
        float f2 = fmaf((float)s2, scl, nb), f3 = fmaf((float)s3, scl, nb);
        float f4 = fmaf((float)s4, scl, nb), f5 = fmaf((float)s5, scl, nb);
        float f6 = fmaf((float)s6, scl, nb), f7 = fmaf((float)s7, scl, nb);
        u32 w0 = (u32)f2b(f0) | ((u32)f2b(f1) << 16);
        u32 w1 = (u32)f2b(f2) | ((u32)f2b(f3) << 16);
        u32 w2 = (u32)f2b(f4) | ((u32)f2b(f5) << 16);
        u32 w3 = (u32)f2b(f6) | ((u32)f2b(f7) << 16);
        *reinterpret_cast<uint4*>((char*)sAB + r * ROWB + ql * 16) = make_uint4(w0, w1, w2, w3);
        if (EMB) {
            if (ql < 8) {
                float e0 = fmaf((float)te0, scl, nb), e1 = fmaf((float)te1, scl, nb);
                *reinterpret_cast<u32*>((char*)sAB + r * ROWB + 256 + ql * 4) =
                    (u32)f2b(e0) | ((u32)f2b(e1) << 16);
            }
        }
    }
    __syncthreads();

    // ---- MFMA GEMM: wave wv covers n-tiles {2wv, 2wv+1}, all 16 rows, K=2D
    const int arow = lane & 15;
    const int kgrp = (lane >> 4) & 3;
    const int nt0 = wv * 2;
    f32x4 acc0 = {0.f, 0.f, 0.f, 0.f}, acc1 = {0.f, 0.f, 0.f, 0.f};
    for (int kt = 0; kt < KT; ++kt) {
        bf16x8 av = *reinterpret_cast<const bf16x8*>((char*)sAB + arow * ROWB + kt * 64 + kgrp * 16);
        bf16x8 b0 = *reinterpret_cast<const bf16x8*>(wp + ((size_t)(kt * 8 + nt0) * 64 + lane) * 8);
        bf16x8 b1 = *reinterpret_cast<const bf16x8*>(wp + ((size_t)(kt * 8 + nt0 + 1) * 64 + lane) * 8);
        acc0 = __builtin_amdgcn_mfma_f32_16x16x32_bf16(av, b0, acc0, 0, 0, 0);
        acc1 = __builtin_amdgcn_mfma_f32_16x16x32_bf16(av, b1, acc1, 0, 0, 0);
    }

    float bias0 = bl[nt0 * 16 + arow], bias1 = bl[nt0 * 16 + 16 + arow];
    if (!HEAD) {
        #pragma unroll
        for (int m = 0; m < 4; ++m) {
            int rr = kgrp * 4 + m;
            if (rr < nrows) {
                int64_t row = block0 + rr;
                float v0 = fmaxf(acc0[m] + bias0, 0.f);
                float v1 = fmaxf(acc1[m] + bias1, 0.f);
                int c0 = nt0 * 16 + arow, c1 = nt0 * 16 + 16 + arow;
                houtb[row * 128 + c0] = f2b(v0);
                houtb[row * 128 + c1] = f2b(v1);
                houtq[row * 128 + c0] = (u8)fq8(v0);
                houtq[row * 128 + c1] = (u8)fq8(v1);
            }
        }
    } else {
        float w0 = Wseg[nt0 * 16 + arow], w1 = Wseg[nt0 * 16 + 16 + arow];
        float p[4];
        #pragma unroll
        for (int m = 0; m < 4; ++m) {
            int rr = kgrp * 4 + m;
            const u16* selfrow = (const u16*)((char*)sAB + rr * ROWB + D * 2);
            float v0 = fmaxf(acc0[m] + bias0, 0.f) + b2f(selfrow[nt0 * 16 + arow]);
            float v1 = fmaxf(acc1[m] + bias1, 0.f) + b2f(selfrow[nt0 * 16 + 16 + arow]);
            p[m] = v0 * w0 + v1 * w1;
        }
        #pragma unroll
        for (int o = 1; o < 16; o <<= 1) {
            p[0] += __shfl_xor(p[0], o, 64);
            p[1] += __shfl_xor(p[1], o, 64);
            p[2] += __shfl_xor(p[2], o, 64);
            p[3] += __shfl_xor(p[3], o, 64);
        }
        if (arow == 0) {
            #pragma unroll
            for (int m = 0; m < 4; ++m) ps[wv][kgrp * 4 + m] = p[m];
        }
        __syncthreads();
        if (tid < 16 && tid < nrows) {
            float s = ps[0][tid] + ps[1][tid] + ps[2][tid] + ps[3][tid];
            int64_t row = block0 + tid;
            if (ACCUM) dout[row] += s + linb[0];
            else dout[row] = s;
        }
    }
}

// ---------------------------------------------------------------- launch
extern "C" void kernel_launch(void* const* d_in, const int* in_sizes, int n_in,
                              void* d_out, int out_size, void* d_ws, size_t ws_size,
                              hipStream_t stream) {
    const float* x       = (const float*)d_in[0];
    const int*   edge_in = (const int*)d_in[1];
    const int*   edge_out= (const int*)d_in[2];
    const float* emb     = (const float*)d_in[3];
    const float* in1_Wl  = (const float*)d_in[4];
    const float* in1_bl  = (const float*)d_in[5];
    const float* in1_Wr  = (const float*)d_in[6];
    const float* in2_Wl  = (const float*)d_in[7];
    const float* in2_bl  = (const float*)d_in[8];
    const float* in2_Wr  = (const float*)d_in[9];
    const float* out1_Wl = (const float*)d_in[10];
    const float* out1_bl = (const float*)d_in[11];
    const float* out1_Wr = (const float*)d_in[12];
    const float* out2_Wl = (const float*)d_in[13];
    const float* out2_bl = (const float*)d_in[14];
    const float* out2_Wr = (const float*)d_in[15];
    const float* lin_W   = (const float*)d_in[16];
    const float* lin_b   = (const float*)d_in[17];

    const int N = in_sizes[0] / 128;
    const int E = in_sizes[1] / 2;
    const int nbk = (N + 15) / 16;
    const int nbins_dir = (N + 511) / 512;
    const int nfine_pad = nbins_dir * 32;

    char* wsb = (char*)d_ws;
    size_t off = 0;
    auto alloc = [&](size_t bytes) {
        char* p = wsb + off;
        off = (off + bytes + 255) & ~(size_t)255;
        return p;
    };
    int* gcnt   = (int*)alloc((size_t)2 * nbins_dir * 4);
    u32* crecs  = (u32*)alloc((size_t)2 * nbins_dir * CAPC * 4);   // 14.5 MB
    int* fcnt_o = (int*)alloc((size_t)nfine_pad * 4);
    int* fcnt_i = (int*)alloc((size_t)nfine_pad * 4);
    u32* recs_o = (u32*)alloc((size_t)nfine_pad * CAPB * 4);       // 12.9 MB
    u32* recs_i = (u32*)alloc((size_t)nfine_pad * CAPB * 4);       // 12.9 MB
    u8*  xq     = (u8*)alloc((size_t)(N + 1) * 128);               // 12.8 MB (+dummy row)
    u8*  embq   = (u8*)alloc((size_t)(N + 1) * 16);                //  1.6 MB
    u16* h1b    = (u16*)alloc((size_t)N * 128 * 2);                // 25.6 MB
    u8*  h1q    = (u8*)alloc((size_t)(N + 1) * 128);               // 12.8 MB
    u16* wp_i1  = (u16*)alloc((size_t)288 * 128 * 2);
    u16* wp_i2  = (u16*)alloc((size_t)256 * 128 * 2);
    u16* wp_o1  = (u16*)alloc((size_t)288 * 128 * 2);
    u16* wp_o2  = (u16*)alloc((size_t)256 * 128 * 2);              // total ~94 MB

    hipMemsetAsync(gcnt, 0, (size_t)2 * nbins_dir * 4, stream);
    // dummy rows (node id N) encode 0.0 => all bytes 128 (0x80)
    hipMemsetAsync(xq + (size_t)N * 128, 0x80, 128, stream);
    hipMemsetAsync(embq + (size_t)N * 16, 0x80, 16, stream);
    hipMemsetAsync(h1q + (size_t)N * 128, 0x80, 128, stream);

    build_q8_k<<<(N * 18 + 255) / 256, 256, 0, stream>>>(x, emb, xq, embq, N);
    pack_w_k<144><<<18, 256, 0, stream>>>(in1_Wl, in1_Wr, wp_i1);
    pack_w_k<128><<<16, 256, 0, stream>>>(in2_Wl, in2_Wr, wp_i2);
    pack_w_k<144><<<18, 256, 0, stream>>>(out1_Wl, out1_Wr, wp_o1);
    pack_w_k<128><<<16, 256, 0, stream>>>(out2_Wl, out2_Wr, wp_o2);

    bin_k<<<(2 * E + EB - 1) / EB, 256, 0, stream>>>(edge_out, edge_in, E,
            nbins_dir, gcnt, crecs);
    split_k<<<2 * nbins_dir, 256, 0, stream>>>(gcnt, crecs, nbins_dir,
            recs_o, fcnt_o, recs_i, fcnt_i);

    // ---- OUT direction: d_out = s_out
    fused_sage<144, false, false><<<nbk, 256, 0, stream>>>(xq, embq, nullptr, x, emb,
            fcnt_o, recs_o, wp_o1, out1_bl, h1b, h1q, nullptr, nullptr, nullptr, N);
    fused_sage<128, true, false><<<nbk, 256, 0, stream>>>(h1q, nullptr, h1b, nullptr, nullptr,
            fcnt_o, recs_o, wp_o2, out2_bl, nullptr, nullptr, (float*)d_out, lin_W + 128, lin_b, N);

    // ---- IN direction: d_out += s_in + b
    fused_sage<144, false, false><<<nbk, 256, 0, stream>>>(xq, embq, nullptr, x, emb,
            fcnt_i, recs_i, wp_i1, in1_bl, h1b, h1q, nullptr, nullptr, nullptr, N);
    fused_sage<128, true, true><<<nbk, 256, 0, stream>>>(h1q, nullptr, h1b, nullptr, nullptr,
            fcnt_i, recs_i, wp_i2, in2_bl, nullptr, nullptr, (float*)d_out, lin_W, lin_b, N);
}

// Round 12
// 336.244 us; speedup vs baseline: 1.0057x; 1.0057x over previous
//
#include <hip/hip_runtime.h>
#include <cstdint>

using u8  = unsigned char;
using u16 = unsigned short;
using u32 = unsigned int;
using bf16x8 = __attribute__((ext_vector_type(8))) short;
using f32x4  = __attribute__((ext_vector_type(4))) float;

#define CAPB 512        // per-fine-bucket (16 nodes) record capacity
#define CAPC 9216       // per-coarse-bin (512 nodes) record capacity
#define EB   8192       // edges per bin_k block
#define SLSZ 800        // slist capacity: 512 + 16*15 pad (752) + ring over-read margin

__device__ __forceinline__ float b2f(u16 b) { return __uint_as_float(((u32)b) << 16); }
__device__ __forceinline__ u16 f2b(float f) {
    u32 u = __float_as_uint(f);
    return (u16)((u + 0x7fff + ((u >> 16) & 1)) >> 16);   // RNE
}
// biased-u8 encode: clamp(rint(x*16),-127,127)+128  ->  [1,255]; 128 == 0.0
__device__ __forceinline__ u32 fq8(float f) {
    float t = fminf(fmaxf(fmaf(f, 16.f, 128.f), 1.f), 255.f);
    return (u32)(t + 0.5f);
}

// ---------------------------------------------------------------- xq (N+1 x 128B) + embq (N+1 x 16B), biased-u8
__global__ __launch_bounds__(256) void build_q8_k(const float* __restrict__ x,
        const float* __restrict__ emb, u8* __restrict__ xq, u8* __restrict__ embq, int N) {
    int t = blockIdx.x * 256 + threadIdx.x;
    if (t >= N * 18) return;
    int i = t / 18, q = t - i * 18;
    const float* s = (q < 16) ? (x + (int64_t)i * 128 + q * 8)
                              : (emb + (int64_t)i * 16 + (q - 16) * 8);
    u32 b0 = fq8(s[0]) | (fq8(s[1]) << 8) | (fq8(s[2]) << 16) | (fq8(s[3]) << 24);
    u32 b1 = fq8(s[4]) | (fq8(s[5]) << 8) | (fq8(s[6]) << 16) | (fq8(s[7]) << 24);
    uint2 w = make_uint2(b0, b1);
    if (q < 16) *reinterpret_cast<uint2*>(xq + (int64_t)i * 128 + q * 8) = w;
    else        *reinterpret_cast<uint2*>(embq + (int64_t)i * 16 + (q - 16) * 8) = w;
}

// ---------------------------------------------------------------- weight B-fragment pack
template<int D>
__global__ __launch_bounds__(256) void pack_w_k(const float* __restrict__ Wl,
        const float* __restrict__ Wr, u16* __restrict__ wp) {
    constexpr int KT = (2 * D) / 32;
    int gid = blockIdx.x * 256 + threadIdx.x;
    if (gid >= KT * 8 * 64) return;
    int lane = gid & 63, nt = (gid >> 6) & 7, kt = gid >> 9;
    int n = nt * 16 + (lane & 15);
    int kb = kt * 32 + ((lane >> 4) & 3) * 8;
    u32 out[4];
    #pragma unroll
    for (int jj = 0; jj < 4; ++jj) {
        int k0 = kb + 2 * jj, k1 = k0 + 1;
        float f0 = (k0 < D) ? Wl[k0 * 128 + n] : Wr[(k0 - D) * 128 + n];
        float f1 = (k1 < D) ? Wl[k1 * 128 + n] : Wr[(k1 - D) * 128 + n];
        out[jj] = (u32)f2b(f0) | ((u32)f2b(f1) << 16);
    }
    *reinterpret_cast<uint4*>(wp + (size_t)gid * 8) = make_uint4(out[0], out[1], out[2], out[3]);
}

// ---------------------------------------------------------------- phase A: coarse bin
__global__ __launch_bounds__(256) void bin_k(const int* __restrict__ eo,
        const int* __restrict__ ei, int E, int nbins_dir,
        int* __restrict__ gcnt, u32* __restrict__ crecs) {
    __shared__ u32 lrec[EB];
    __shared__ u16 lkey[EB];
    __shared__ int lcnt[392], gbase[392], lpos[392];
    const int tid = threadIdx.x;
    const int nbins = 2 * nbins_dir;
    for (int i = tid; i < nbins; i += 256) lcnt[i] = 0;
    __syncthreads();
    const int base = blockIdx.x * EB;
    const int nrec = min(EB, 2 * E - base);
    #pragma unroll 4
    for (int t = tid; t < nrec; t += 256) {
        int g = base + t;
        int dir = (g >= E) ? 1 : 0;
        int e = g - dir * E;
        const int* ed = dir ? ei : eo;
        int s = ed[e], d = ed[E + e];
        int key = dir * nbins_dir + (d >> 9);
        lrec[t] = ((u32)(d & 511) << 20) | (u32)s;
        lkey[t] = (u16)key;
        atomicAdd(&lcnt[key], 1);
    }
    __syncthreads();
    for (int i = tid; i < nbins; i += 256) {
        lpos[i] = 0;
        gbase[i] = lcnt[i] ? atomicAdd(&gcnt[i], lcnt[i]) : 0;
    }
    __syncthreads();
    #pragma unroll 4
    for (int t = tid; t < nrec; t += 256) {
        int key = lkey[t];
        int pos = gbase[key] + atomicAdd(&lpos[key], 1);
        if (pos < CAPC) crecs[(size_t)key * CAPC + pos] = lrec[t];
    }
}

// ---------------------------------------------------------------- phase B: split coarse -> fine
__global__ __launch_bounds__(256) void split_k(const int* __restrict__ gcnt,
        const u32* __restrict__ crecs, int nbins_dir,
        u32* __restrict__ recs_o, int* __restrict__ fcnt_o,
        u32* __restrict__ recs_i, int* __restrict__ fcnt_i) {
    __shared__ u32 lsort[CAPC];
    __shared__ int lcnt[32], lrp[32], lcur[32];
    const int tid = threadIdx.x;
    const int c = blockIdx.x;
    const int dir = c / nbins_dir;
    const int bin = c - dir * nbins_dir;
    u32* recs = dir ? recs_i : recs_o;
    int* fcnt = dir ? fcnt_i : fcnt_o;
    const int n = min(gcnt[c], CAPC);
    const u32* rb = crecs + (size_t)c * CAPC;
    if (tid < 32) { lcnt[tid] = 0; lcur[tid] = 0; }
    __syncthreads();
    for (int t = tid; t < n; t += 256) atomicAdd(&lcnt[rb[t] >> 24], 1);
    __syncthreads();
    if (tid == 0) {
        int run = 0;
        #pragma unroll
        for (int i = 0; i < 32; ++i) { lrp[i] = run; run += lcnt[i]; }
    }
    __syncthreads();
    for (int t = tid; t < n; t += 256) {
        u32 rc = rb[t];
        int fb = rc >> 24;
        lsort[lrp[fb] + atomicAdd(&lcur[fb], 1)] = ((rc >> 20) & 15u) << 27 | (rc & 0xFFFFFu);
    }
    __syncthreads();
    #pragma unroll
    for (int fb = 0; fb < 32; ++fb) {
        int fine = bin * 32 + fb;
        int cnt = min(lcnt[fb], CAPB);
        u32* dst = recs + (size_t)fine * CAPB;
        for (int t = tid; t < cnt; t += 256) dst[t] = lsort[lrp[fb] + t];
        if (tid == 0) fcnt[fine] = cnt;
    }
}

// ---------------------------------------------------------------- fused SAGE layer
// Balanced gather: the wave processes its 4 nodes SEQUENTIALLY; per node all 4
// quarters cooperate (4 edges in flight, depth-4 ring, wave-uniform trip count, no
// divergence). Per-node list padded to a MULTIPLE OF 16 so the ring's commit count
// (4*cg4 = 16*ceil(cj/16)) exactly equals the padded region -- every committed slot
// is a real edge or a dummy-N slot (0.0 row), absorbed by the -128*(4*cg4) de-bias.
// SWAR u8 accumulate; widen to u32; cross-quarter shfl_xor(16,32) reduce.
// MFMA GEMM vs packed [Wl;Wr] K=2D. HEAD: +residual (bf16 self), head dot.
template<int D, bool HEAD, bool ACCUM>
__global__ __launch_bounds__(256) void fused_sage(
        const u8* __restrict__ srcq,                 // biased-u8 gather table, stride 128
        const u8* __restrict__ embq,                 // biased-u8 emb table, stride 16 (layer 1)
        const u16* __restrict__ selfb,               // bf16 self table (layer 2)
        const float* __restrict__ xf, const float* __restrict__ ef, // layer-1 self
        const int* __restrict__ bcnt, const u32* __restrict__ recs,
        const u16* __restrict__ wp, const float* __restrict__ bl,
        u16* __restrict__ houtb, u8* __restrict__ houtq,
        float* __restrict__ dout,
        const float* __restrict__ Wseg, const float* __restrict__ linb, int N) {
    constexpr bool EMB = (D == 144);
    constexpr int K = 2 * D;
    constexpr int KT = K / 32;
    constexpr int ROWB = 592;
    __shared__ u16 sAB[16 * (ROWB / 2)];
    __shared__ u32 rbuf[CAPB];
    __shared__ u32 slist[SLSZ];
    __shared__ int ncnt[16], nrp[16], ncur[16];
    __shared__ float ps[4][16];
    const int tid = threadIdx.x;
    const int lane = tid & 63;
    const int wv = tid >> 6;
    const int q = lane >> 4;
    const int ql = lane & 15;
    const int64_t block0 = (int64_t)blockIdx.x * 16;
    const int nrows = (int)min((int64_t)16, (int64_t)N - block0);

    // ---- stage self rows (bf16) at byte offset 2*D; pre-fill slist with dummy N
    for (int t = tid; t < SLSZ; t += 256) slist[t] = (u32)N;
    if (EMB) {
        for (int f = tid; f < 16 * 36; f += 256) {
            int r = f / 36, c = f - r * 36;
            if (r < nrows) {
                float4 v = (c < 32)
                    ? reinterpret_cast<const float4*>(xf)[(block0 + r) * 32 + c]
                    : reinterpret_cast<const float4*>(ef)[(block0 + r) * 4 + (c - 32)];
                u32 lo = (u32)f2b(v.x) | ((u32)f2b(v.y) << 16);
                u32 hi = (u32)f2b(v.z) | ((u32)f2b(v.w) << 16);
                *reinterpret_cast<uint2*>((char*)sAB + r * ROWB + D * 2 + c * 8) = make_uint2(lo, hi);
            }
        }
    } else {
        for (int f = tid; f < 16 * 16; f += 256) {
            int r = f / 16, c = f - r * 16;
            if (r < nrows) {
                uint4 v = reinterpret_cast<const uint4*>(selfb + (block0 + r) * 128)[c];
                *reinterpret_cast<uint4*>((char*)sAB + r * ROWB + D * 2 + c * 16) = v;
            }
        }
    }
    if (tid < 16) ncnt[tid] = 0;

    // ---- load records, counting sort into per-node lists (each padded to mult of 16)
    const int n = min(bcnt[blockIdx.x], CAPB);
    const u32* rb = recs + (size_t)blockIdx.x * CAPB;
    for (int t = tid; t < n; t += 256) rbuf[t] = rb[t];
    __syncthreads();
    for (int t = tid; t < n; t += 256) atomicAdd(&ncnt[rbuf[t] >> 27], 1);
    __syncthreads();
    if (tid == 0) {
        int run = 0;
        #pragma unroll
        for (int i = 0; i < 16; ++i) { nrp[i] = run; run += (ncnt[i] + 15) & ~15; }
    }
    if (tid < 16) ncur[tid] = 0;
    __syncthreads();
    for (int t = tid; t < n; t += 256) {
        u32 rc = rbuf[t];
        int dl = rc >> 27;
        slist[nrp[dl] + atomicAdd(&ncur[dl], 1)] = rc & 0x07ffffffu;
    }
    __syncthreads();

    // ---- balanced gather: wave's 4 nodes sequential; 4 edges/step, depth-4 ring
    const u8* basem = srcq + ql * 8;
    const u8* basee = embq + (ql & 7) * 2;
#define LOADK(GG, MM, TT)                                                          \
        {                                                                          \
            u32 so_ = slist[offq + (GG) * 4];                                      \
            MM = *reinterpret_cast<const uint2*>(basem + ((size_t)so_ << 7));      \
            if (EMB) TT = (ql < 8) ? (u32)*reinterpret_cast<const u16*>(basee + ((size_t)so_ << 4)) : 0u; \
        }
#define COMMITK(MM, TT)                                                            \
        {                                                                          \
            aE0 += MM.x & 0x00FF00FFu; aO0 += (MM.x >> 8) & 0x00FF00FFu;           \
            aE1 += MM.y & 0x00FF00FFu; aO1 += (MM.y >> 8) & 0x00FF00FFu;           \
            if (EMB) { te0 += TT & 0xffu; te1 += TT >> 8; }                        \
        }
    #pragma unroll
    for (int j = 0; j < 4; ++j) {
        const int r = wv * 4 + j;
        const int cj = ncnt[r];
        const int ng = (cj + 3) >> 2;                // groups of 4 edges
        const int cg4 = (ng + 3) & ~3;               // committed groups; 4*cg4 == padded len
        const int offq = nrp[r] + q;                 // this quarter's member slot
        u32 aE0 = 0, aO0 = 0, aE1 = 0, aO1 = 0;      // 2x16-bit SWAR (max 128*255 < 64K)
        u32 te0 = 0, te1 = 0;
        uint2 m0, m1, m2, m3;
        u32 t0 = 0, t1 = 0, t2 = 0, t3 = 0;
        LOADK(0, m0, t0) LOADK(1, m1, t1) LOADK(2, m2, t2) LOADK(3, m3, t3)
        for (int g = 0; g < ng; g += 4) {
            COMMITK(m0, t0) LOADK(g + 4, m0, t0)
            COMMITK(m1, t1) LOADK(g + 5, m1, t1)
            COMMITK(m2, t2) LOADK(g + 6, m2, t2)
            COMMITK(m3, t3) LOADK(g + 7, m3, t3)
        }
        // widen to u32 halves, then cross-quarter reduce (xor 16, 32)
        u32 s0 = aE0 & 0xffffu, s2 = aE0 >> 16;
        u32 s1 = aO0 & 0xffffu, s3 = aO0 >> 16;
        u32 s4 = aE1 & 0xffffu, s6 = aE1 >> 16;
        u32 s5 = aO1 & 0xffffu, s7 = aO1 >> 16;
        s0 += __shfl_xor(s0, 16, 64); s1 += __shfl_xor(s1, 16, 64);
        s2 += __shfl_xor(s2, 16, 64); s3 += __shfl_xor(s3, 16, 64);
        s4 += __shfl_xor(s4, 16, 64); s5 += __shfl_xor(s5, 16, 64);
        s6 += __shfl_xor(s6, 16, 64); s7 += __shfl_xor(s7, 16, 64);
        s0 += __shfl_xor(s0, 32, 64); s1 += __shfl_xor(s1, 32, 64);
        s2 += __shfl_xor(s2, 32, 64); s3 += __shfl_xor(s3, 32, 64);
        s4 += __shfl_xor(s4, 32, 64); s5 += __shfl_xor(s5, 32, 64);
        s6 += __shfl_xor(s6, 32, 64); s7 += __shfl_xor(s7, 32, 64);
        if (EMB) {
            te0 += __shfl_xor(te0, 16, 64); te1 += __shfl_xor(te1, 16, 64);
            te0 += __shfl_xor(te0, 32, 64); te1 += __shfl_xor(te1, 32, 64);
        }
        if (q == j) {
            const float scl = 1.0f / (16.0f * (float)max(cj, 1));
            const float nb = -128.0f * (float)(cg4 * 4) * scl;   // 4 quarters x cg4 commits
            float f0 = fmaf((float)s0, scl, nb), f1 = fmaf((float)s1, scl, nb);
            float f2 = fmaf((float)s2, scl, nb), f3 = fmaf((float)s3, scl, nb);
            float f4 = fmaf((float)s4, scl, nb), f5 = fmaf((float)s5, scl, nb);
            float f6 = fmaf((float)s6, scl, nb), f7 = fmaf((float)s7, scl, nb);
            u32 w0 = (u32)f2b(f0) | ((u32)f2b(f1) << 16);
            u32 w1 = (u32)f2b(f2) | ((u32)f2b(f3) << 16);
            u32 w2 = (u32)f2b(f4) | ((u32)f2b(f5) << 16);
            u32 w3 = (u32)f2b(f6) | ((u32)f2b(f7) << 16);
            *reinterpret_cast<uint4*>((char*)sAB + r * ROWB + ql * 16) = make_uint4(w0, w1, w2, w3);
            if (EMB) {
                if (ql < 8) {
                    float e0 = fmaf((float)te0, scl, nb), e1 = fmaf((float)te1, scl, nb);
                    *reinterpret_cast<u32*>((char*)sAB + r * ROWB + 256 + ql * 4) =
                        (u32)f2b(e0) | ((u32)f2b(e1) << 16);
                }
            }
        }
    }
#undef LOADK
#undef COMMITK
    __syncthreads();

    // ---- MFMA GEMM: wave wv covers n-tiles {2wv, 2wv+1}, all 16 rows, K=2D
    const int arow = lane & 15;
    const int kgrp = (lane >> 4) & 3;
    const int nt0 = wv * 2;
    f32x4 acc0 = {0.f, 0.f, 0.f, 0.f}, acc1 = {0.f, 0.f, 0.f, 0.f};
    for (int kt = 0; kt < KT; ++kt) {
        bf16x8 av = *reinterpret_cast<const bf16x8*>((char*)sAB + arow * ROWB + kt * 64 + kgrp * 16);
        bf16x8 b0 = *reinterpret_cast<const bf16x8*>(wp + ((size_t)(kt * 8 + nt0) * 64 + lane) * 8);
        bf16x8 b1 = *reinterpret_cast<const bf16x8*>(wp + ((size_t)(kt * 8 + nt0 + 1) * 64 + lane) * 8);
        acc0 = __builtin_amdgcn_mfma_f32_16x16x32_bf16(av, b0, acc0, 0, 0, 0);
        acc1 = __builtin_amdgcn_mfma_f32_16x16x32_bf16(av, b1, acc1, 0, 0, 0);
    }

    float bias0 = bl[nt0 * 16 + arow], bias1 = bl[nt0 * 16 + 16 + arow];
    if (!HEAD) {
        #pragma unroll
        for (int m = 0; m < 4; ++m) {
            int rr = kgrp * 4 + m;
            if (rr < nrows) {
                int64_t row = block0 + rr;
                float v0 = fmaxf(acc0[m] + bias0, 0.f);
                float v1 = fmaxf(acc1[m] + bias1, 0.f);
                int c0 = nt0 * 16 + arow, c1 = nt0 * 16 + 16 + arow;
                houtb[row * 128 + c0] = f2b(v0);
                houtb[row * 128 + c1] = f2b(v1);
                houtq[row * 128 + c0] = (u8)fq8(v0);
                houtq[row * 128 + c1] = (u8)fq8(v1);
            }
        }
    } else {
        float w0 = Wseg[nt0 * 16 + arow], w1 = Wseg[nt0 * 16 + 16 + arow];
        float p[4];
        #pragma unroll
        for (int m = 0; m < 4; ++m) {
            int rr = kgrp * 4 + m;
            const u16* selfrow = (const u16*)((char*)sAB + rr * ROWB + D * 2);
            float v0 = fmaxf(acc0[m] + bias0, 0.f) + b2f(selfrow[nt0 * 16 + arow]);
            float v1 = fmaxf(acc1[m] + bias1, 0.f) + b2f(selfrow[nt0 * 16 + 16 + arow]);
            p[m] = v0 * w0 + v1 * w1;
        }
        #pragma unroll
        for (int o = 1; o < 16; o <<= 1) {
            p[0] += __shfl_xor(p[0], o, 64);
            p[1] += __shfl_xor(p[1], o, 64);
            p[2] += __shfl_xor(p[2], o, 64);
            p[3] += __shfl_xor(p[3], o, 64);
        }
        if (arow == 0) {
            #pragma unroll
            for (int m = 0; m < 4; ++m) ps[wv][kgrp * 4 + m] = p[m];
        }
        __syncthreads();
        if (tid < 16 && tid < nrows) {
            float s = ps[0][tid] + ps[1][tid] + ps[2][tid] + ps[3][tid];
            int64_t row = block0 + tid;
            if (ACCUM) dout[row] += s + linb[0];
            else dout[row] = s;
        }
    }
}

// ---------------------------------------------------------------- launch
extern "C" void kernel_launch(void* const* d_in, const int* in_sizes, int n_in,
                              void* d_out, int out_size, void* d_ws, size_t ws_size,
                              hipStream_t stream) {
    const float* x       = (const float*)d_in[0];
    const int*   edge_in = (const int*)d_in[1];
    const int*   edge_out= (const int*)d_in[2];
    const float* emb     = (const float*)d_in[3];
    const float* in1_Wl  = (const float*)d_in[4];
    const float* in1_bl  = (const float*)d_in[5];
    const float* in1_Wr  = (const float*)d_in[6];
    const float* in2_Wl  = (const float*)d_in[7];
    const float* in2_bl  = (const float*)d_in[8];
    const float* in2_Wr  = (const float*)d_in[9];
    const float* out1_Wl = (const float*)d_in[10];
    const float* out1_bl = (const float*)d_in[11];
    const float* out1_Wr = (const float*)d_in[12];
    const float* out2_Wl = (const float*)d_in[13];
    const float* out2_bl = (const float*)d_in[14];
    const float* out2_Wr = (const float*)d_in[15];
    const float* lin_W   = (const float*)d_in[16];
    const float* lin_b   = (const float*)d_in[17];

    const int N = in_sizes[0] / 128;
    const int E = in_sizes[1] / 2;
    const int nbk = (N + 15) / 16;
    const int nbins_dir = (N + 511) / 512;
    const int nfine_pad = nbins_dir * 32;

    char* wsb = (char*)d_ws;
    size_t off = 0;
    auto alloc = [&](size_t bytes) {
        char* p = wsb + off;
        off = (off + bytes + 255) & ~(size_t)255;
        return p;
    };
    int* gcnt   = (int*)alloc((size_t)2 * nbins_dir * 4);
    u32* crecs  = (u32*)alloc((size_t)2 * nbins_dir * CAPC * 4);   // 14.5 MB
    int* fcnt_o = (int*)alloc((size_t)nfine_pad * 4);
    int* fcnt_i = (int*)alloc((size_t)nfine_pad * 4);
    u32* recs_o = (u32*)alloc((size_t)nfine_pad * CAPB * 4);       // 12.9 MB
    u32* recs_i = (u32*)alloc((size_t)nfine_pad * CAPB * 4);       // 12.9 MB
    u8*  xq     = (u8*)alloc((size_t)(N + 1) * 128);               // 12.8 MB (+dummy row)
    u8*  embq   = (u8*)alloc((size_t)(N + 1) * 16);                //  1.6 MB
    u16* h1b    = (u16*)alloc((size_t)N * 128 * 2);                // 25.6 MB
    u8*  h1q    = (u8*)alloc((size_t)(N + 1) * 128);               // 12.8 MB
    u16* wp_i1  = (u16*)alloc((size_t)288 * 128 * 2);
    u16* wp_i2  = (u16*)alloc((size_t)256 * 128 * 2);
    u16* wp_o1  = (u16*)alloc((size_t)288 * 128 * 2);
    u16* wp_o2  = (u16*)alloc((size_t)256 * 128 * 2);              // total ~94 MB

    hipMemsetAsync(gcnt, 0, (size_t)2 * nbins_dir * 4, stream);
    // dummy rows (node id N) encode 0.0 => all bytes 128 (0x80)
    hipMemsetAsync(xq + (size_t)N * 128, 0x80, 128, stream);
    hipMemsetAsync(embq + (size_t)N * 16, 0x80, 16, stream);
    hipMemsetAsync(h1q + (size_t)N * 128, 0x80, 128, stream);

    build_q8_k<<<(N * 18 + 255) / 256, 256, 0, stream>>>(x, emb, xq, embq, N);
    pack_w_k<144><<<18, 256, 0, stream>>>(in1_Wl, in1_Wr, wp_i1);
    pack_w_k<128><<<16, 256, 0, stream>>>(in2_Wl, in2_Wr, wp_i2);
    pack_w_k<144><<<18, 256, 0, stream>>>(out1_Wl, out1_Wr, wp_o1);
    pack_w_k<128><<<16, 256, 0, stream>>>(out2_Wl, out2_Wr, wp_o2);

    bin_k<<<(2 * E + EB - 1) / EB, 256, 0, stream>>>(edge_out, edge_in, E,
            nbins_dir, gcnt, crecs);
    split_k<<<2 * nbins_dir, 256, 0, stream>>>(gcnt, crecs, nbins_dir,
            recs_o, fcnt_o, recs_i, fcnt_i);

    // ---- OUT direction: d_out = s_out
    fused_sage<144, false, false><<<nbk, 256, 0, stream>>>(xq, embq, nullptr, x, emb,
            fcnt_o, recs_o, wp_o1, out1_bl, h1b, h1q, nullptr, nullptr, nullptr, N);
    fused_sage<128, true, false><<<nbk, 256, 0, stream>>>(h1q, nullptr, h1b, nullptr, nullptr,
            fcnt_o, recs_o, wp_o2, out2_bl, nullptr, nullptr, (float*)d_out, lin_W + 128, lin_b, N);

    // ---- IN direction: d_out += s_in + b
    fused_sage<144, false, false><<<nbk, 256, 0, stream>>>(xq, embq, nullptr, x, emb,
            fcnt_i, recs_i, wp_i1, in1_bl, h1b, h1q, nullptr, nullptr, nullptr, N);
    fused_sage<128, true, true><<<nbk, 256, 0, stream>>>(h1q, nullptr, h1b, nullptr, nullptr,
            fcnt_i, recs_i, wp_i2, in2_bl, nullptr, nullptr, (float*)d_out, lin_W, lin_b, N);
}

// Round 13
// 300.457 us; speedup vs baseline: 1.1255x; 1.1191x over previous
//
#include <hip/hip_runtime.h>
#include <cstdint>

using u8  = unsigned char;
using u16 = unsigned short;
using u32 = unsigned int;
using bf16x8 = __attribute__((ext_vector_type(8))) short;
using f32x4  = __attribute__((ext_vector_type(4))) float;
typedef float f32x2 __attribute__((ext_vector_type(2)));

#define CAPB 512        // per-fine-bucket (16 nodes) record capacity
#define CAPC 9216       // per-coarse-bin (512 nodes) record capacity
#define EB   8192       // edges per bin_k block

__device__ __forceinline__ float b2f(u16 b) { return __uint_as_float(((u32)b) << 16); }
__device__ __forceinline__ u16 f2b(float f) {
    u32 u = __float_as_uint(f);
    return (u16)((u + 0x7fff + ((u >> 16) & 1)) >> 16);   // RNE
}

// ---------------------------------------------------------------- xb8 (N x 128B) + emb8 (N x 16B), fp8
__global__ __launch_bounds__(256) void build_xb8_k(const float* __restrict__ x,
        const float* __restrict__ emb, u8* __restrict__ xb8, u8* __restrict__ emb8, int N) {
    int t = blockIdx.x * 256 + threadIdx.x;
    if (t >= N * 18) return;
    int i = t / 18, q = t - i * 18;
    const float* s = (q < 16) ? (x + (int64_t)i * 128 + q * 8)
                              : (emb + (int64_t)i * 16 + (q - 16) * 8);
    float4 v0 = *reinterpret_cast<const float4*>(s);
    float4 v1 = *reinterpret_cast<const float4*>(s + 4);
    int p0 = __builtin_amdgcn_cvt_pk_fp8_f32(v0.x, v0.y, 0, false);
    int p1 = __builtin_amdgcn_cvt_pk_fp8_f32(v0.z, v0.w, 0, false);
    int p2 = __builtin_amdgcn_cvt_pk_fp8_f32(v1.x, v1.y, 0, false);
    int p3 = __builtin_amdgcn_cvt_pk_fp8_f32(v1.z, v1.w, 0, false);
    u32 lo = (u32)(p0 & 0xffff) | ((u32)(p1 & 0xffff) << 16);
    u32 hi = (u32)(p2 & 0xffff) | ((u32)(p3 & 0xffff) << 16);
    uint2 w = make_uint2(lo, hi);
    if (q < 16) *reinterpret_cast<uint2*>(xb8 + (int64_t)i * 128 + q * 8) = w;
    else        *reinterpret_cast<uint2*>(emb8 + (int64_t)i * 16 + (q - 16) * 8) = w;
}

// ---------------------------------------------------------------- weight B-fragment pack
template<int D>
__global__ __launch_bounds__(256) void pack_w_k(const float* __restrict__ Wl,
        const float* __restrict__ Wr, u16* __restrict__ wp) {
    constexpr int KT = (2 * D) / 32;
    int gid = blockIdx.x * 256 + threadIdx.x;
    if (gid >= KT * 8 * 64) return;
    int lane = gid & 63, nt = (gid >> 6) & 7, kt = gid >> 9;
    int n = nt * 16 + (lane & 15);
    int kb = kt * 32 + ((lane >> 4) & 3) * 8;
    u32 out[4];
    #pragma unroll
    for (int jj = 0; jj < 4; ++jj) {
        int k0 = kb + 2 * jj, k1 = k0 + 1;
        float f0 = (k0 < D) ? Wl[k0 * 128 + n] : Wr[(k0 - D) * 128 + n];
        float f1 = (k1 < D) ? Wl[k1 * 128 + n] : Wr[(k1 - D) * 128 + n];
        out[jj] = (u32)f2b(f0) | ((u32)f2b(f1) << 16);
    }
    *reinterpret_cast<uint4*>(wp + (size_t)gid * 8) = make_uint4(out[0], out[1], out[2], out[3]);
}

// ---------------------------------------------------------------- phase A: coarse bin
__global__ __launch_bounds__(256) void bin_k(const int* __restrict__ eo,
        const int* __restrict__ ei, int E, int nbins_dir,
        int* __restrict__ gcnt, u32* __restrict__ crecs) {
    __shared__ u32 lrec[EB];
    __shared__ u16 lkey[EB];
    __shared__ int lcnt[392], gbase[392], lpos[392];
    const int tid = threadIdx.x;
    const int nbins = 2 * nbins_dir;
    for (int i = tid; i < nbins; i += 256) lcnt[i] = 0;
    __syncthreads();
    const int base = blockIdx.x * EB;
    const int nrec = min(EB, 2 * E - base);
    #pragma unroll 4
    for (int t = tid; t < nrec; t += 256) {
        int g = base + t;
        int dir = (g >= E) ? 1 : 0;
        int e = g - dir * E;
        const int* ed = dir ? ei : eo;
        int s = ed[e], d = ed[E + e];
        int key = dir * nbins_dir + (d >> 9);
        lrec[t] = ((u32)(d & 511) << 20) | (u32)s;
        lkey[t] = (u16)key;
        atomicAdd(&lcnt[key], 1);
    }
    __syncthreads();
    for (int i = tid; i < nbins; i += 256) {
        lpos[i] = 0;
        gbase[i] = lcnt[i] ? atomicAdd(&gcnt[i], lcnt[i]) : 0;
    }
    __syncthreads();
    #pragma unroll 4
    for (int t = tid; t < nrec; t += 256) {
        int key = lkey[t];
        int pos = gbase[key] + atomicAdd(&lpos[key], 1);
        if (pos < CAPC) crecs[(size_t)key * CAPC + pos] = lrec[t];
    }
}

// ---------------------------------------------------------------- phase B: split coarse -> fine
__global__ __launch_bounds__(256) void split_k(const int* __restrict__ gcnt,
        const u32* __restrict__ crecs, int nbins_dir,
        u32* __restrict__ recs_o, int* __restrict__ fcnt_o,
        u32* __restrict__ recs_i, int* __restrict__ fcnt_i) {
    __shared__ u32 lsort[CAPC];
    __shared__ int lcnt[32], lrp[32], lcur[32];
    const int tid = threadIdx.x;
    const int c = blockIdx.x;
    const int dir = c / nbins_dir;
    const int bin = c - dir * nbins_dir;
    u32* recs = dir ? recs_i : recs_o;
    int* fcnt = dir ? fcnt_i : fcnt_o;
    const int n = min(gcnt[c], CAPC);
    const u32* rb = crecs + (size_t)c * CAPC;
    if (tid < 32) { lcnt[tid] = 0; lcur[tid] = 0; }
    __syncthreads();
    for (int t = tid; t < n; t += 256) atomicAdd(&lcnt[rb[t] >> 24], 1);
    __syncthreads();
    if (tid == 0) {
        int run = 0;
        #pragma unroll
        for (int i = 0; i < 32; ++i) { lrp[i] = run; run += lcnt[i]; }
    }
    __syncthreads();
    for (int t = tid; t < n; t += 256) {
        u32 rc = rb[t];
        int fb = rc >> 24;
        lsort[lrp[fb] + atomicAdd(&lcur[fb], 1)] = ((rc >> 20) & 15u) << 27 | (rc & 0xFFFFFu);
    }
    __syncthreads();
    #pragma unroll
    for (int fb = 0; fb < 32; ++fb) {
        int fine = bin * 32 + fb;
        int cnt = min(lcnt[fb], CAPB);
        u32* dst = recs + (size_t)fine * CAPB;
        for (int t = tid; t < cnt; t += 256) dst[t] = lsort[lrp[fb] + t];
        if (tid == 0) fcnt[fine] = cnt;
    }
}

// ---------------------------------------------------------------- fused SAGE layer
// r9 structure + degree-grouped quarter assignment: nodes ranked by degree (desc);
// wave wv's quarters handle ranks wv*4..wv*4+3 -> similar degrees share a wave, so
// the wave's masked gather loop (trip = max of 4 degrees) wastes ~8% instead of ~35%.
// Gather: quarter owns one node; depth-6 static ring over fp8 128B rows (+ 16B
// L2-resident emb rows for layer 1); masked validity; f32 accumulate -> mean ->
// bf16 A-tile. MFMA GEMM vs packed [Wl;Wr] K=2D. HEAD: +residual, head dot.
template<int D, bool HEAD, bool ACCUM>
__global__ __launch_bounds__(256) void fused_sage(
        const u8* __restrict__ src8,                 // fp8 gather table, stride 128
        const u8* __restrict__ emb8,                 // fp8 emb table, stride 16 (layer 1)
        const u16* __restrict__ selfb,               // bf16 self table (layer 2)
        const float* __restrict__ xf, const float* __restrict__ ef, // layer-1 self
        const int* __restrict__ bcnt, const u32* __restrict__ recs,
        const u16* __restrict__ wp, const float* __restrict__ bl,
        u16* __restrict__ houtb, u8* __restrict__ houtq,
        float* __restrict__ dout,
        const float* __restrict__ Wseg, const float* __restrict__ linb, int N) {
    constexpr bool EMB = (D == 144);
    constexpr int K = 2 * D;
    constexpr int KT = K / 32;
    constexpr int ROWB = 592;
    __shared__ u16 sAB[16 * (ROWB / 2)];
    __shared__ u32 rbuf[CAPB];
    __shared__ u32 slist[CAPB + 16];
    __shared__ int ncnt[16], nrp[16], ncur[16], perm[16];
    __shared__ float ps[4][16];
    const int tid = threadIdx.x;
    const int lane = tid & 63;
    const int wv = tid >> 6;
    const int q = lane >> 4;
    const int ql = lane & 15;
    const int64_t block0 = (int64_t)blockIdx.x * 16;
    const int nrows = (int)min((int64_t)16, (int64_t)N - block0);

    // ---- stage self rows (bf16) at byte offset 2*D
    if (EMB) {
        for (int f = tid; f < 16 * 36; f += 256) {
            int r = f / 36, c = f - r * 36;
            if (r < nrows) {
                float4 v = (c < 32)
                    ? reinterpret_cast<const float4*>(xf)[(block0 + r) * 32 + c]
                    : reinterpret_cast<const float4*>(ef)[(block0 + r) * 4 + (c - 32)];
                u32 lo = (u32)f2b(v.x) | ((u32)f2b(v.y) << 16);
                u32 hi = (u32)f2b(v.z) | ((u32)f2b(v.w) << 16);
                *reinterpret_cast<uint2*>((char*)sAB + r * ROWB + D * 2 + c * 8) = make_uint2(lo, hi);
            }
        }
    } else {
        for (int f = tid; f < 16 * 16; f += 256) {
            int r = f / 16, c = f - r * 16;
            if (r < nrows) {
                uint4 v = reinterpret_cast<const uint4*>(selfb + (block0 + r) * 128)[c];
                *reinterpret_cast<uint4*>((char*)sAB + r * ROWB + D * 2 + c * 16) = v;
            }
        }
    }
    if (tid < 16) ncnt[tid] = 0;

    // ---- load records, counting sort into per-node lists
    const int n = min(bcnt[blockIdx.x], CAPB);
    const u32* rb = recs + (size_t)blockIdx.x * CAPB;
    for (int t = tid; t < n; t += 256) rbuf[t] = rb[t];
    __syncthreads();
    for (int t = tid; t < n; t += 256) atomicAdd(&ncnt[rbuf[t] >> 27], 1);
    __syncthreads();
    if (tid == 0) {
        int run = 0;
        #pragma unroll
        for (int i = 0; i < 16; ++i) { nrp[i] = run; run += ncnt[i]; }
    }
    if (tid < 16) {
        ncur[tid] = 0;
        // degree rank (desc, index tie-break); perm[rank] = node
        int my = ncnt[tid];
        int rank = 0;
        #pragma unroll
        for (int j = 0; j < 16; ++j) {
            int dj = ncnt[j];
            rank += (dj > my) || (dj == my && j < tid);
        }
        perm[rank] = tid;
    }
    __syncthreads();
    for (int t = tid; t < n; t += 256) {
        u32 rc = rbuf[t];
        int dl = rc >> 27;
        slist[nrp[dl] + atomicAdd(&ncur[dl], 1)] = rc & 0x07ffffffu;
    }
    __syncthreads();

    // ---- gather: quarter q of wave wv owns node perm[wv*4+q]; depth-6 static ring
    const int r = perm[wv * 4 + q];
    const int cj = ncnt[r], off = nrp[r];
    float a[8] = {0,0,0,0,0,0,0,0};
    float e0 = 0.f, e1 = 0.f;
    const u8* basem = src8 + ql * 8;
    const u8* basee = emb8 + (ql & 7) * 2;
    {
        uint2 m0, m1, m2, m3, m4, m5;
        u32 t0 = 0, t1 = 0, t2 = 0, t3 = 0, t4 = 0, t5 = 0;
#define LOADK(KK, MM, TT)                                                          \
        {                                                                          \
            int kk_ = (KK);                                                        \
            u32 so_ = slist[off + kk_];                                            \
            MM = make_uint2(0, 0); TT = 0;                                         \
            if (kk_ < cj) {                                                        \
                MM = *reinterpret_cast<const uint2*>(basem + ((size_t)so_ << 7));  \
                if (EMB) { if (ql < 8) TT = *reinterpret_cast<const u16*>(basee + ((size_t)so_ << 4)); } \
            }                                                                      \
        }
#define COMMITK(MM, TT)                                                            \
        {                                                                          \
            f32x2 p0 = __builtin_amdgcn_cvt_pk_f32_fp8((int)MM.x, false);          \
            f32x2 p1 = __builtin_amdgcn_cvt_pk_f32_fp8((int)MM.x, true);           \
            f32x2 p2 = __builtin_amdgcn_cvt_pk_f32_fp8((int)MM.y, false);          \
            f32x2 p3 = __builtin_amdgcn_cvt_pk_f32_fp8((int)MM.y, true);           \
            a[0] += p0[0]; a[1] += p0[1]; a[2] += p1[0]; a[3] += p1[1];            \
            a[4] += p2[0]; a[5] += p2[1]; a[6] += p3[0]; a[7] += p3[1];            \
            if (EMB) { f32x2 pe = __builtin_amdgcn_cvt_pk_f32_fp8((int)TT, false); \
                       e0 += pe[0]; e1 += pe[1]; }                                 \
        }
        LOADK(0, m0, t0) LOADK(1, m1, t1) LOADK(2, m2, t2)
        LOADK(3, m3, t3) LOADK(4, m4, t4) LOADK(5, m5, t5)
        for (int k = 0; k < cj; k += 6) {
            COMMITK(m0, t0) LOADK(k + 6,  m0, t0)
            COMMITK(m1, t1) LOADK(k + 7,  m1, t1)
            COMMITK(m2, t2) LOADK(k + 8,  m2, t2)
            COMMITK(m3, t3) LOADK(k + 9,  m3, t3)
            COMMITK(m4, t4) LOADK(k + 10, m4, t4)
            COMMITK(m5, t5) LOADK(k + 11, m5, t5)
        }
#undef LOADK
#undef COMMITK
    }

    // ---- mean -> bf16 staging row r
    {
        float rinv = 1.0f / fmaxf((float)cj, 1.0f);
        u32 w0 = (u32)f2b(a[0] * rinv) | ((u32)f2b(a[1] * rinv) << 16);
        u32 w1 = (u32)f2b(a[2] * rinv) | ((u32)f2b(a[3] * rinv) << 16);
        u32 w2 = (u32)f2b(a[4] * rinv) | ((u32)f2b(a[5] * rinv) << 16);
        u32 w3 = (u32)f2b(a[6] * rinv) | ((u32)f2b(a[7] * rinv) << 16);
        *reinterpret_cast<uint4*>((char*)sAB + r * ROWB + ql * 16) = make_uint4(w0, w1, w2, w3);
        if (EMB) {
            if (ql < 8) {
                u32 we = (u32)f2b(e0 * rinv) | ((u32)f2b(e1 * rinv) << 16);
                *reinterpret_cast<u32*>((char*)sAB + r * ROWB + 256 + ql * 4) = we;
            }
        }
    }
    __syncthreads();

    // ---- MFMA GEMM: wave wv covers n-tiles {2wv, 2wv+1}, all 16 rows, K=2D
    const int arow = lane & 15;
    const int kgrp = (lane >> 4) & 3;
    const int nt0 = wv * 2;
    f32x4 acc0 = {0.f, 0.f, 0.f, 0.f}, acc1 = {0.f, 0.f, 0.f, 0.f};
    for (int kt = 0; kt < KT; ++kt) {
        bf16x8 av = *reinterpret_cast<const bf16x8*>((char*)sAB + arow * ROWB + kt * 64 + kgrp * 16);
        bf16x8 b0 = *reinterpret_cast<const bf16x8*>(wp + ((size_t)(kt * 8 + nt0) * 64 + lane) * 8);
        bf16x8 b1 = *reinterpret_cast<const bf16x8*>(wp + ((size_t)(kt * 8 + nt0 + 1) * 64 + lane) * 8);
        acc0 = __builtin_amdgcn_mfma_f32_16x16x32_bf16(av, b0, acc0, 0, 0, 0);
        acc1 = __builtin_amdgcn_mfma_f32_16x16x32_bf16(av, b1, acc1, 0, 0, 0);
    }

    float bias0 = bl[nt0 * 16 + arow], bias1 = bl[nt0 * 16 + 16 + arow];
    if (!HEAD) {
        #pragma unroll
        for (int m = 0; m < 4; ++m) {
            int rr = kgrp * 4 + m;
            if (rr < nrows) {
                int64_t row = block0 + rr;
                float v0 = fmaxf(acc0[m] + bias0, 0.f);
                float v1 = fmaxf(acc1[m] + bias1, 0.f);
                int c0 = nt0 * 16 + arow, c1 = nt0 * 16 + 16 + arow;
                houtb[row * 128 + c0] = f2b(v0);
                houtb[row * 128 + c1] = f2b(v1);
                int pk = __builtin_amdgcn_cvt_pk_fp8_f32(v0, v1, 0, false);
                houtq[row * 128 + c0] = (u8)(pk & 0xff);
                houtq[row * 128 + c1] = (u8)((pk >> 8) & 0xff);
            }
        }
    } else {
        float w0 = Wseg[nt0 * 16 + arow], w1 = Wseg[nt0 * 16 + 16 + arow];
        float p[4];
        #pragma unroll
        for (int m = 0; m < 4; ++m) {
            int rr = kgrp * 4 + m;
            const u16* selfrow = (const u16*)((char*)sAB + rr * ROWB + D * 2);
            float v0 = fmaxf(acc0[m] + bias0, 0.f) + b2f(selfrow[nt0 * 16 + arow]);
            float v1 = fmaxf(acc1[m] + bias1, 0.f) + b2f(selfrow[nt0 * 16 + 16 + arow]);
            p[m] = v0 * w0 + v1 * w1;
        }
        #pragma unroll
        for (int o = 1; o < 16; o <<= 1) {
            p[0] += __shfl_xor(p[0], o, 64);
            p[1] += __shfl_xor(p[1], o, 64);
            p[2] += __shfl_xor(p[2], o, 64);
            p[3] += __shfl_xor(p[3], o, 64);
        }
        if (arow == 0) {
            #pragma unroll
            for (int m = 0; m < 4; ++m) ps[wv][kgrp * 4 + m] = p[m];
        }
        __syncthreads();
        if (tid < 16 && tid < nrows) {
            float s = ps[0][tid] + ps[1][tid] + ps[2][tid] + ps[3][tid];
            int64_t row = block0 + tid;
            if (ACCUM) dout[row] += s + linb[0];
            else dout[row] = s;
        }
    }
}

// ---------------------------------------------------------------- launch
extern "C" void kernel_launch(void* const* d_in, const int* in_sizes, int n_in,
                              void* d_out, int out_size, void* d_ws, size_t ws_size,
                              hipStream_t stream) {
    const float* x       = (const float*)d_in[0];
    const int*   edge_in = (const int*)d_in[1];
    const int*   edge_out= (const int*)d_in[2];
    const float* emb     = (const float*)d_in[3];
    const float* in1_Wl  = (const float*)d_in[4];
    const float* in1_bl  = (const float*)d_in[5];
    const float* in1_Wr  = (const float*)d_in[6];
    const float* in2_Wl  = (const float*)d_in[7];
    const float* in2_bl  = (const float*)d_in[8];
    const float* in2_Wr  = (const float*)d_in[9];
    const float* out1_Wl = (const float*)d_in[10];
    const float* out1_bl = (const float*)d_in[11];
    const float* out1_Wr = (const float*)d_in[12];
    const float* out2_Wl = (const float*)d_in[13];
    const float* out2_bl = (const float*)d_in[14];
    const float* out2_Wr = (const float*)d_in[15];
    const float* lin_W   = (const float*)d_in[16];
    const float* lin_b   = (const float*)d_in[17];

    const int N = in_sizes[0] / 128;
    const int E = in_sizes[1] / 2;
    const int nbk = (N + 15) / 16;
    const int nbins_dir = (N + 511) / 512;
    const int nfine_pad = nbins_dir * 32;

    char* wsb = (char*)d_ws;
    size_t off = 0;
    auto alloc = [&](size_t bytes) {
        char* p = wsb + off;
        off = (off + bytes + 255) & ~(size_t)255;
        return p;
    };
    int* gcnt   = (int*)alloc((size_t)2 * nbins_dir * 4);
    u32* crecs  = (u32*)alloc((size_t)2 * nbins_dir * CAPC * 4);   // 14.5 MB
    int* fcnt_o = (int*)alloc((size_t)nfine_pad * 4);
    int* fcnt_i = (int*)alloc((size_t)nfine_pad * 4);
    u32* recs_o = (u32*)alloc((size_t)nfine_pad * CAPB * 4);       // 12.9 MB
    u32* recs_i = (u32*)alloc((size_t)nfine_pad * CAPB * 4);       // 12.9 MB
    u8*  xb8    = (u8*)alloc((size_t)N * 128);                     // 12.8 MB
    u8*  emb8   = (u8*)alloc((size_t)N * 16);                      //  1.6 MB
    u16* h1b    = (u16*)alloc((size_t)N * 128 * 2);                // 25.6 MB
    u8*  h1q    = (u8*)alloc((size_t)N * 128);                     // 12.8 MB
    u16* wp_i1  = (u16*)alloc((size_t)288 * 128 * 2);
    u16* wp_i2  = (u16*)alloc((size_t)256 * 128 * 2);
    u16* wp_o1  = (u16*)alloc((size_t)288 * 128 * 2);
    u16* wp_o2  = (u16*)alloc((size_t)256 * 128 * 2);              // total ~94 MB

    hipMemsetAsync(gcnt, 0, (size_t)2 * nbins_dir * 4, stream);
    build_xb8_k<<<(N * 18 + 255) / 256, 256, 0, stream>>>(x, emb, xb8, emb8, N);
    pack_w_k<144><<<18, 256, 0, stream>>>(in1_Wl, in1_Wr, wp_i1);
    pack_w_k<128><<<16, 256, 0, stream>>>(in2_Wl, in2_Wr, wp_i2);
    pack_w_k<144><<<18, 256, 0, stream>>>(out1_Wl, out1_Wr, wp_o1);
    pack_w_k<128><<<16, 256, 0, stream>>>(out2_Wl, out2_Wr, wp_o2);

    bin_k<<<(2 * E + EB - 1) / EB, 256, 0, stream>>>(edge_out, edge_in, E,
            nbins_dir, gcnt, crecs);
    split_k<<<2 * nbins_dir, 256, 0, stream>>>(gcnt, crecs, nbins_dir,
            recs_o, fcnt_o, recs_i, fcnt_i);

    // ---- OUT direction: d_out = s_out
    fused_sage<144, false, false><<<nbk, 256, 0, stream>>>(xb8, emb8, nullptr, x, emb,
            fcnt_o, recs_o, wp_o1, out1_bl, h1b, h1q, nullptr, nullptr, nullptr, N);
    fused_sage<128, true, false><<<nbk, 256, 0, stream>>>(h1q, nullptr, h1b, nullptr, nullptr,
            fcnt_o, recs_o, wp_o2, out2_bl, nullptr, nullptr, (float*)d_out, lin_W + 128, lin_b, N);

    // ---- IN direction: d_out += s_in + b
    fused_sage<144, false, false><<<nbk, 256, 0, stream>>>(xb8, emb8, nullptr, x, emb,
            fcnt_i, recs_i, wp_i1, in1_bl, h1b, h1q, nullptr, nullptr, nullptr, N);
    fused_sage<128, true, true><<<nbk, 256, 0, stream>>>(h1q, nullptr, h1b, nullptr, nullptr,
            fcnt_i, recs_i, wp_i2, in2_bl, nullptr, nullptr, (float*)d_out, lin_W, lin_b, N);
}